// Round 3
// baseline (2761.003 us; speedup 1.0000x reference)
//
#include <hip/hip_runtime.h>
#include <cstdint>
#include <cstddef>

#define T_LEN 1024
#define CH    1024
#define NGATE 4096
#define LAT   128
#define NBLK  128   // cooperative LSTM blocks; each owns 8 hidden dims

// ---------------- ws layout (bytes) ----------------
// [0, 16 MiB)   : xg[T][4096]        precomputed input gates (+biases)
// [+0 KiB]      : hbuf64[2][1024]    tagged h broadcast (u64: tag<<32 | bits)
// [+16 KiB]     : hfin64[1024]       tagged final h (tag==1)
// [+24 KiB]     : cfin64[1024]       tagged final c (tag==1)
// [+32 KiB]     : ctrl[1] : {eos_idx}
#define WS_XG    0
#define WS_HBUF  (16777216)
#define WS_HFIN  (16777216 + 16384)
#define WS_CFIN  (16777216 + 24576)
#define WS_CTRL  (16777216 + 32768)

// LDS swizzle (CORRECTED): float j stored at j ^ (((j>>5)&7)<<2).
// Read side, lane ln slot m (float4 granules): base = ln*16+4m, base>>5 = ln>>1,
// so 16B-slot index = (m + 4*(ln&1)) ^ ((ln>>1)&7) — a permutation of 0..7
// across every 8 consecutive lanes for fixed m (verified by enumeration).
// Write side (b32): within each 32-lane half, tid>>5 is constant -> XOR with a
// constant -> distinct banks. Bits 0-1 untouched -> float4 stays contiguous.
#define SWZ(j) ((j) ^ ((((j) >> 5) & 7) << 2))

// ---- fast gate math: v_exp_f32 (2^x) + v_rcp_f32, graceful saturation ----
#define LOG2E 1.44269504088896340736f
__device__ __forceinline__ float fsig(float x) {   // 1/(1+e^-x)
  return __builtin_amdgcn_rcpf(1.0f + __builtin_amdgcn_exp2f(-LOG2E * x));
}
__device__ __forceinline__ float ftanh(float x) {  // 1 - 2/(e^{2x}+1)
  float e = __builtin_amdgcn_exp2f(2.0f * LOG2E * x);
  return 1.0f - 2.0f * __builtin_amdgcn_rcpf(e + 1.0f);
}

__device__ __forceinline__ float sigmf(float x) { return 1.0f / (1.0f + expf(-x)); }

template <int CTRL, int RM>
__device__ __forceinline__ float dpp_add(float x) {
  int t = __builtin_amdgcn_update_dpp(0, __float_as_int(x), CTRL, RM, 0xf, true);
  return x + __int_as_float(t);
}

// 64-lane sum via DPP (VALU pipe only, no DS ops). Result valid in lane 63.
__device__ __forceinline__ float wave_sum63(float x) {
  x = dpp_add<0x111, 0xf>(x);   // row_shr:1
  x = dpp_add<0x112, 0xf>(x);   // row_shr:2
  x = dpp_add<0x114, 0xf>(x);   // row_shr:4
  x = dpp_add<0x118, 0xf>(x);   // row_shr:8  -> lane15 of each row = row sum
  x = dpp_add<0x142, 0xa>(x);   // row_bcast:15 -> rows 1,3
  x = dpp_add<0x143, 0xc>(x);   // row_bcast:31 -> rows 2,3; lane 63 = total
  return x;
}

// Raw barrier: orders LDS only (lgkmcnt), leaves vmcnt outstanding so the
// poll pipeline's dead in-flight loads drain during the matvec instead of
// stalling at the barrier (the h exchange is tag-self-synchronizing; global
// loads are waited at their uses by the compiler's dependence tracking).
__device__ __forceinline__ void bar_lgkm() {
  asm volatile("s_waitcnt lgkmcnt(0)" ::: "memory");
  __builtin_amdgcn_s_barrier();
  __builtin_amdgcn_sched_barrier(0);
}

__device__ __forceinline__ unsigned long long apoll(const unsigned long long* p) {
  return __hip_atomic_load(p, __ATOMIC_RELAXED, __HIP_MEMORY_SCOPE_AGENT);
}

// ---------------- kernel A: eos index ----------------
__global__ __launch_bounds__(1024) void setup_k(const int* __restrict__ tok,
                                                int* __restrict__ ctrl) {
  __shared__ int red[1024];
  int tid = threadIdx.x;
  red[tid] = (tok[tid] == 1) ? tid : 0x7fffffff;
  __syncthreads();
  for (int s = 512; s > 0; s >>= 1) {
    if (tid < s) red[tid] = min(red[tid], red[tid + s]);
    __syncthreads();
  }
  if (tid == 0) {
    int e = red[0];
    ctrl[0] = (e == 0x7fffffff) ? 0 : e;   // argmax of all-false is 0
  }
}

// ---------------- kernel B: xg = gather(emb) @ W_ih^T + b_ih + b_hh ----------------
// C[t][r], tiles 128(t) x 128(r), 512 threads, 4x8 microtile, K-chunk 16.
__global__ __launch_bounds__(512) void xgemm_k(const int* __restrict__ tok,
                                               const float* __restrict__ emb,
                                               const float* __restrict__ Wih,
                                               const float* __restrict__ bih,
                                               const float* __restrict__ bhh,
                                               float* __restrict__ xg) {
  __shared__ float As[16 * 132];   // As[k][m] transposed, pad 132
  __shared__ float Bs[16 * 132];   // Bs[k][n]
  const int tid = threadIdx.x;
  const int r0 = blockIdx.x * 128;
  const int t0 = blockIdx.y * 128;
  const int tx = tid & 15, ty = tid >> 4;     // tx: r micro (8), ty: t micro (4)
  const int m0 = ty * 4, n0 = tx * 8;
  const int lrow = tid >> 2;                  // 0..127 loader row
  const int kq   = (tid & 3) * 4;             // 0,4,8,12

  float acc[4][8];
#pragma unroll
  for (int i = 0; i < 4; i++)
#pragma unroll
    for (int j = 0; j < 8; j++) acc[i][j] = 0.0f;

  const int tokv = tok[t0 + lrow];
  const float* arow = emb + (size_t)tokv * CH;
  const float* brow = Wih + (size_t)(r0 + lrow) * CH;

  for (int k0 = 0; k0 < CH; k0 += 16) {
    float4 a4 = *(const float4*)(arow + k0 + kq);
    float4 b4 = *(const float4*)(brow + k0 + kq);
    __syncthreads();   // previous iter's LDS reads complete
    As[(kq + 0) * 132 + lrow] = a4.x;
    As[(kq + 1) * 132 + lrow] = a4.y;
    As[(kq + 2) * 132 + lrow] = a4.z;
    As[(kq + 3) * 132 + lrow] = a4.w;
    Bs[(kq + 0) * 132 + lrow] = b4.x;
    Bs[(kq + 1) * 132 + lrow] = b4.y;
    Bs[(kq + 2) * 132 + lrow] = b4.z;
    Bs[(kq + 3) * 132 + lrow] = b4.w;
    __syncthreads();
#pragma unroll
    for (int kk = 0; kk < 16; kk++) {
      float4 av = *(const float4*)&As[kk * 132 + m0];
      float4 b0 = *(const float4*)&Bs[kk * 132 + n0];
      float4 b1 = *(const float4*)&Bs[kk * 132 + n0 + 4];
      float aa[4] = {av.x, av.y, av.z, av.w};
      float bb[8] = {b0.x, b0.y, b0.z, b0.w, b1.x, b1.y, b1.z, b1.w};
#pragma unroll
      for (int i = 0; i < 4; i++)
#pragma unroll
        for (int j = 0; j < 8; j++) acc[i][j] += aa[i] * bb[j];
    }
  }

  float4 bi0 = *(const float4*)(bih + r0 + n0);
  float4 bi1 = *(const float4*)(bih + r0 + n0 + 4);
  float4 bh0 = *(const float4*)(bhh + r0 + n0);
  float4 bh1 = *(const float4*)(bhh + r0 + n0 + 4);
  float badd[8] = {bi0.x + bh0.x, bi0.y + bh0.y, bi0.z + bh0.z, bi0.w + bh0.w,
                   bi1.x + bh1.x, bi1.y + bh1.y, bi1.z + bh1.z, bi1.w + bh1.w};
#pragma unroll
  for (int i = 0; i < 4; i++) {
    float4 o0 = {acc[i][0] + badd[0], acc[i][1] + badd[1],
                 acc[i][2] + badd[2], acc[i][3] + badd[3]};
    float4 o1 = {acc[i][4] + badd[4], acc[i][5] + badd[5],
                 acc[i][6] + badd[6], acc[i][7] + badd[7]};
    float* dst = xg + (size_t)(t0 + m0 + i) * NGATE + r0 + n0;
    *(float4*)(dst) = o0;
    *(float4*)(dst + 4) = o1;
  }
}

// ---------------- kernel C: cooperative LSTM + projections ----------------
// 128 blocks x 1024 threads. Block b owns hidden dims [b*8, b*8+8).
//
// Round-2 matvec structure kept (off critical path). Round-3 changes target
// the measured serial chain:
//  - 4-deep pipelined poll: 4 outstanding same-address relaxed atomic loads,
//    checked oldest-first -> detection granularity ~L/4 instead of L.
//  - Raw lgkm-only barriers in the step loop: no vmcnt(0) drain, so the
//    poll pipeline's dead loads retire under the matvec.
//  - Fast v_exp/v_rcp gates (exp2 form): serial transcendental chain
//    ~250cy -> ~50cy.
//  - Corrected hs swizzle (round-2's collided; conflicts counter proved it).
//
// Cross-block h exchange: fence-free tagged 64-bit relaxed device-scope atomics.
// Payload = (tag<<32)|float_bits; tag t+1 published into slot (t+1)&1.
// D=2 double-buffer is race-free: publishing tag t+2 requires having consumed
// ALL tags t+1, which implies every block finished reading slot t&1. While
// polling for tag t, slot (t&1) can only hold tag t-2 (stale) or t, so any
// load observing tag t carries the correct payload.
__global__ __launch_bounds__(1024) void lstm_k(const float* __restrict__ h0,
                                               const float* __restrict__ c0,
                                               const float* __restrict__ eps,
                                               const float* __restrict__ Whh,
                                               const float* __restrict__ Wm,
                                               const float* __restrict__ bm,
                                               const float* __restrict__ Wl,
                                               const float* __restrict__ bl,
                                               const float* __restrict__ xg,
                                               unsigned long long* __restrict__ hbuf64,
                                               unsigned long long* __restrict__ hfin64,
                                               unsigned long long* __restrict__ cfin64,
                                               const int* __restrict__ ctrl,
                                               float* __restrict__ out) {
  __shared__ float hs[1024];
  __shared__ float hcs[2048];
  __shared__ float4 gpart[16];
  __shared__ float rs[32];

  const int tid = threadIdx.x;
  const int b = blockIdx.x;
  const int wv = tid >> 6;   // wave 0..15
  const int ln = tid & 63;   // lane
  const int dw = wv & 7;     // dim (within block) this wave serves
  const int mb = (wv >> 3) * 2;          // float4 slots {mb, mb+1}
  const int hsw = SWZ(tid);              // swizzled hs slot for this thread
  const int swzmask = ((ln >> 1) & 7) << 2;
  const int idx0 = (ln * 16 + 4 * mb) ^ swzmask;
  const int idx1 = (ln * 16 + 4 * mb + 4) ^ swzmask;

  // weight fragments: rows q*1024 + b*8 + dw, k = ln*16 + 4*{mb,mb+1}
  float4 w4[4][2];
#pragma unroll
  for (int q = 0; q < 4; q++) {
    const float* wr = Whh + (size_t)(q * 1024 + b * 8 + dw) * CH + ln * 16 + 4 * mb;
    w4[q][0] = *(const float4*)(wr);
    w4[q][1] = *(const float4*)(wr + 4);
  }

  const int eos = ctrl[0];

  float hreg = 0.0f, creg = 0.0f;
  if (tid < 8) { hreg = h0[b * 8 + tid]; creg = c0[b * 8 + tid]; }

  for (int t = 0; t < eos; t++) {
    // prefetch this step's input-gate values; hidden under the poll latency
    float xq0 = 0.0f, xq1 = 0.0f, xq2 = 0.0f, xq3 = 0.0f;
    if (tid < 8) {
      const float* xp = xg + (size_t)t * NGATE + b * 8 + tid;
      xq0 = xp[0]; xq1 = xp[1024]; xq2 = xp[2048]; xq3 = xp[3072];
    }

    if (t == 0) {
      hs[hsw] = h0[tid];
    } else {
      const unsigned want = (unsigned)t;
      const unsigned long long* src = hbuf64 + (size_t)(t & 1) * 1024 + tid;
      // 4-deep pipelined poll: keep 4 loads in flight, check oldest first.
      unsigned long long v0 = apoll(src), v1 = apoll(src),
                         v2 = apoll(src), v3 = apoll(src);
      unsigned long long got;
      for (;;) {
        if ((unsigned)(v0 >> 32) == want) { got = v0; break; }
        v0 = apoll(src);
        if ((unsigned)(v1 >> 32) == want) { got = v1; break; }
        v1 = apoll(src);
        if ((unsigned)(v2 >> 32) == want) { got = v2; break; }
        v2 = apoll(src);
        if ((unsigned)(v3 >> 32) == want) { got = v3; break; }
        v3 = apoll(src);
      }
      hs[hsw] = __uint_as_float((unsigned)(got & 0xffffffffu));
    }
    bar_lgkm();   // hs visible; vmcnt left outstanding (drains under matvec)

    // partial matvec: this wave's m-slice of dim dw's four gate rows
    float a0 = 0.0f, a1 = 0.0f, a2 = 0.0f, a3 = 0.0f;
    {
      const float4 h4a = *(const float4*)&hs[idx0];
      const float4 h4b = *(const float4*)&hs[idx1];
      a0 += w4[0][0].x * h4a.x; a0 += w4[0][0].y * h4a.y;
      a0 += w4[0][0].z * h4a.z; a0 += w4[0][0].w * h4a.w;
      a0 += w4[0][1].x * h4b.x; a0 += w4[0][1].y * h4b.y;
      a0 += w4[0][1].z * h4b.z; a0 += w4[0][1].w * h4b.w;
      a1 += w4[1][0].x * h4a.x; a1 += w4[1][0].y * h4a.y;
      a1 += w4[1][0].z * h4a.z; a1 += w4[1][0].w * h4a.w;
      a1 += w4[1][1].x * h4b.x; a1 += w4[1][1].y * h4b.y;
      a1 += w4[1][1].z * h4b.z; a1 += w4[1][1].w * h4b.w;
      a2 += w4[2][0].x * h4a.x; a2 += w4[2][0].y * h4a.y;
      a2 += w4[2][0].z * h4a.z; a2 += w4[2][0].w * h4a.w;
      a2 += w4[2][1].x * h4b.x; a2 += w4[2][1].y * h4b.y;
      a2 += w4[2][1].z * h4b.z; a2 += w4[2][1].w * h4b.w;
      a3 += w4[3][0].x * h4a.x; a3 += w4[3][0].y * h4a.y;
      a3 += w4[3][0].z * h4a.z; a3 += w4[3][0].w * h4a.w;
      a3 += w4[3][1].x * h4b.x; a3 += w4[3][1].y * h4b.y;
      a3 += w4[3][1].z * h4b.z; a3 += w4[3][1].w * h4b.w;
    }
    a0 = wave_sum63(a0);
    a1 = wave_sum63(a1);
    a2 = wave_sum63(a2);
    a3 = wave_sum63(a3);
    if (ln == 63) gpart[wv] = float4{a0, a1, a2, a3};
    bar_lgkm();   // gpart ready; also retires hs reads before next writes

    if (tid < 8) {
      const float4 g0 = gpart[tid];
      const float4 g1 = gpart[tid + 8];
      const float iv = g0.x + g1.x + xq0;
      const float fv = g0.y + g1.y + xq1;
      const float gg = g0.z + g1.z + xq2;
      const float ov = g0.w + g1.w + xq3;
      const float cn = fsig(fv) * creg + fsig(iv) * ftanh(gg);
      const float hn = fsig(ov) * ftanh(cn);
      creg = cn; hreg = hn;
      const unsigned long long pv =
          ((unsigned long long)(unsigned)(t + 1) << 32) |
          (unsigned long long)__float_as_uint(hn);
      __hip_atomic_store(&hbuf64[(size_t)((t + 1) & 1) * 1024 + b * 8 + tid], pv,
                         __ATOMIC_RELAXED, __HIP_MEMORY_SCOPE_AGENT);
    }
  }

  // publish final h, c into dedicated tagged buffers (tag == 1; poison never matches)
  if (tid < 8) {
    const unsigned long long ph = (1ull << 32) | (unsigned long long)__float_as_uint(hreg);
    const unsigned long long pc = (1ull << 32) | (unsigned long long)__float_as_uint(creg);
    __hip_atomic_store(&hfin64[b * 8 + tid], ph, __ATOMIC_RELAXED, __HIP_MEMORY_SCOPE_AGENT);
    __hip_atomic_store(&cfin64[b * 8 + tid], pc, __ATOMIC_RELAXED, __HIP_MEMORY_SCOPE_AGENT);
  }

  // gather full hc = concat(h, c)
  {
    unsigned long long vh, vc;
    do {
      vh = __hip_atomic_load(&hfin64[tid], __ATOMIC_RELAXED, __HIP_MEMORY_SCOPE_AGENT);
    } while ((unsigned)(vh >> 32) != 1u);
    do {
      vc = __hip_atomic_load(&cfin64[tid], __ATOMIC_RELAXED, __HIP_MEMORY_SCOPE_AGENT);
    } while ((unsigned)(vc >> 32) != 1u);
    hcs[tid] = __uint_as_float((unsigned)(vh & 0xffffffffu));
    hcs[1024 + tid] = __uint_as_float((unsigned)(vc & 0xffffffffu));
  }
  __syncthreads();

  // projections: block b computes mean[b], logv[b] (2048-dot each)
  float hc1 = hcs[tid];
  float hc2 = hcs[1024 + tid];
  float pm = Wm[(size_t)b * 2048 + tid] * hc1 + Wm[(size_t)b * 2048 + 1024 + tid] * hc2;
  float pl = Wl[(size_t)b * 2048 + tid] * hc1 + Wl[(size_t)b * 2048 + 1024 + tid] * hc2;
#pragma unroll
  for (int o = 32; o > 0; o >>= 1) {
    pm += __shfl_down(pm, o);
    pl += __shfl_down(pl, o);
  }
  if (ln == 0) { rs[wv] = pm; rs[16 + wv] = pl; }
  __syncthreads();
  if (tid == 0) {
    float m = 0.0f, l = 0.0f;
    for (int i = 0; i < 16; i++) { m += rs[i]; l += rs[16 + i]; }
    m += bm[b];
    l += bl[b];
    float z = eps[b] * expf(0.5f * l) + m;
    out[b] = z;
    out[LAT + b] = m;
    out[2 * LAT + b] = l;
  }
}

extern "C" void kernel_launch(void* const* d_in, const int* in_sizes, int n_in,
                              void* d_out, int out_size, void* d_ws, size_t ws_size,
                              hipStream_t stream) {
  const int*   tok = (const int*)d_in[0];
  const float* h0  = (const float*)d_in[1];
  const float* c0  = (const float*)d_in[2];
  const float* eps = (const float*)d_in[3];
  const float* emb = (const float*)d_in[4];
  const float* Wih = (const float*)d_in[5];
  const float* Whh = (const float*)d_in[6];
  const float* bih = (const float*)d_in[7];
  const float* bhh = (const float*)d_in[8];
  const float* Wm  = (const float*)d_in[9];
  const float* bm  = (const float*)d_in[10];
  const float* Wl  = (const float*)d_in[11];
  const float* bl  = (const float*)d_in[12];
  float* out = (float*)d_out;

  char* ws = (char*)d_ws;
  float* xg = (float*)(ws + WS_XG);
  unsigned long long* hbuf64 = (unsigned long long*)(ws + WS_HBUF);
  unsigned long long* hfin64 = (unsigned long long*)(ws + WS_HFIN);
  unsigned long long* cfin64 = (unsigned long long*)(ws + WS_CFIN);
  int* ctrl = (int*)(ws + WS_CTRL);

  setup_k<<<1, 1024, 0, stream>>>(tok, ctrl);
  xgemm_k<<<dim3(NGATE / 128, T_LEN / 128), 512, 0, stream>>>(tok, emb, Wih, bih, bhh, xg);

  void* args[] = {(void*)&h0, (void*)&c0, (void*)&eps, (void*)&Whh,
                  (void*)&Wm, (void*)&bm, (void*)&Wl, (void*)&bl,
                  (void*)&xg, (void*)&hbuf64, (void*)&hfin64, (void*)&cfin64,
                  (void*)&ctrl, (void*)&out};
  hipLaunchCooperativeKernel((void*)lstm_k, dim3(NBLK), dim3(1024), args, 0, stream);
}

// Round 4
// 2362.558 us; speedup vs baseline: 1.1686x; 1.1686x over previous
//
#include <hip/hip_runtime.h>
#include <cstdint>
#include <cstddef>

#define T_LEN 1024
#define CH    1024
#define NGATE 4096
#define LAT   128
#define NBLK  128   // cooperative LSTM blocks; each owns 8 hidden dims

// ---------------- ws layout (bytes) ----------------
// [0, 16 MiB)   : (unused; was xg)
// [+0 KiB]      : hbuf64[2][1024]    tagged h broadcast (u64: tag<<32 | bits)
// [+16 KiB]     : hfin64[1024]       tagged final h (tag==1)
// [+24 KiB]     : cfin64[1024]       tagged final c (tag==1)
#define WS_HBUF  (16777216)
#define WS_HFIN  (16777216 + 16384)
#define WS_CFIN  (16777216 + 24576)

// LDS swizzle: float j stored at j ^ (((j>>5)&7)<<2).  Read side, lane ln,
// 16B slot index = (m + 4*(ln&1)) ^ ((ln>>1)&7): permutation of 0..7 across
// every 8 lanes. Write side (b32): tid>>5 constant per half-wave -> XOR with
// a constant -> distinct banks. Bits 0-1 untouched -> float4 contiguous.
#define SWZ(j) ((j) ^ ((((j) >> 5) & 7) << 2))

__device__ __forceinline__ float sigmf(float x) { return 1.0f / (1.0f + expf(-x)); }

template <int CTRL, int RM>
__device__ __forceinline__ float dpp_add(float x) {
  int t = __builtin_amdgcn_update_dpp(0, __float_as_int(x), CTRL, RM, 0xf, true);
  return x + __int_as_float(t);
}

// 64-lane sum via DPP (VALU pipe only, no DS ops). Result valid in lane 63.
__device__ __forceinline__ float wave_sum63(float x) {
  x = dpp_add<0x111, 0xf>(x);   // row_shr:1
  x = dpp_add<0x112, 0xf>(x);   // row_shr:2
  x = dpp_add<0x114, 0xf>(x);   // row_shr:4
  x = dpp_add<0x118, 0xf>(x);   // row_shr:8  -> lane15 of each row = row sum
  x = dpp_add<0x142, 0xa>(x);   // row_bcast:15 -> rows 1,3
  x = dpp_add<0x143, 0xc>(x);   // row_bcast:31 -> rows 2,3; lane 63 = total
  return x;
}

// ---------------- fused cooperative kernel ----------------
// 128 blocks x 1024 threads. Block b owns hidden dims [b*8, b*8+8).
//
// vs the 2460us baseline: setup_k and xgemm_k are DELETED. The input-gate
// contribution x_t @ W_ih^T is computed inline each step (32 FMAs/thread,
// hidden in the poll dead-time); eos reduction runs in the prologue.
// The exchange loop itself is the baseline's measured-good config verbatim:
// 1-deep poll, plain __syncthreads, exact libm gates.
//
// Register budget: w4 (Whh slice, 32f) + wx (Wih slice, 32f) + working.
// __launch_bounds__(1024, 4) -> 4 waves/SIMD -> 128-VGPR cap, 1 block/CU
// (128 blocks on 256 CUs: extra occupancy is worthless here).
//
// Cross-block h exchange: fence-free tagged 64-bit relaxed device-scope atomics.
// Payload = (tag<<32)|float_bits; tag t+1 published into slot (t+1)&1.
// D=2 double-buffer is race-free: publishing tag t+2 requires having consumed
// ALL tags t+1, which implies every block finished reading slot t&1.
__global__ __launch_bounds__(1024, 4) void lstm_k(const int* __restrict__ tok,
                                                  const float* __restrict__ h0,
                                                  const float* __restrict__ c0,
                                                  const float* __restrict__ eps,
                                                  const float* __restrict__ emb,
                                                  const float* __restrict__ Wih,
                                                  const float* __restrict__ Whh,
                                                  const float* __restrict__ bih,
                                                  const float* __restrict__ bhh,
                                                  const float* __restrict__ Wm,
                                                  const float* __restrict__ bm,
                                                  const float* __restrict__ Wl,
                                                  const float* __restrict__ bl,
                                                  unsigned long long* __restrict__ hbuf64,
                                                  unsigned long long* __restrict__ hfin64,
                                                  unsigned long long* __restrict__ cfin64,
                                                  float* __restrict__ out) {
  __shared__ float hs[1024];
  __shared__ float hcs[2048];
  __shared__ float4 gpart[16];
  __shared__ float rs[32];
  __shared__ int red[1024];

  const int tid = threadIdx.x;
  const int b = blockIdx.x;
  const int wv = tid >> 6;   // wave 0..15
  const int ln = tid & 63;   // lane
  const int dw = wv & 7;     // dim (within block) this wave serves
  const int mb = (wv >> 3) * 2;          // float4 slots {mb, mb+1}
  const int kbase = ln * 16 + 4 * mb;    // this thread's 8-float k-window
  const int hsw = SWZ(tid);              // swizzled hs slot for this thread
  const int swzmask = ((ln >> 1) & 7) << 2;
  const int idx0 = kbase ^ swzmask;
  const int idx1 = (kbase + 4) ^ swzmask;

  // ---- eos index (inlined; all blocks compute it redundantly) ----
  red[tid] = (tok[tid] == 1) ? tid : 0x7fffffff;
  __syncthreads();
  for (int s = 512; s > 0; s >>= 1) {
    if (tid < s) red[tid] = min(red[tid], red[tid + s]);
    __syncthreads();
  }
  const int e0 = red[0];
  const int eos = (e0 == 0x7fffffff) ? 0 : e0;
  __syncthreads();

  // ---- weight fragments: rows q*1024 + b*8 + dw, k in [kbase, kbase+8) ----
  float4 w4[4][2];   // W_hh slice
  float4 wx[4][2];   // W_ih slice
#pragma unroll
  for (int q = 0; q < 4; q++) {
    const size_t roff = (size_t)(q * 1024 + b * 8 + dw) * CH + kbase;
    w4[q][0] = *(const float4*)(Whh + roff);
    w4[q][1] = *(const float4*)(Whh + roff + 4);
    wx[q][0] = *(const float4*)(Wih + roff);
    wx[q][1] = *(const float4*)(Wih + roff + 4);
  }

  // ---- per-dim biases (tid<8 only): bias[q] for gate rows q*1024+b*8+tid ----
  float bias[4] = {0.f, 0.f, 0.f, 0.f};
  if (tid < 8) {
#pragma unroll
    for (int q = 0; q < 4; q++) {
      const int r = q * 1024 + b * 8 + tid;
      bias[q] = bih[r] + bhh[r];
    }
  }

  float hreg = 0.0f, creg = 0.0f;
  if (tid < 8) { hreg = h0[b * 8 + tid]; creg = c0[b * 8 + tid]; }

  for (int t = 0; t < eos; t++) {
    // x_t fragment: issued BEFORE the poll so the load latency hides under it
    const int tokv = tok[t];
    const float* xrow = emb + (size_t)tokv * CH + kbase;
    const float4 x4a = *(const float4*)(xrow);
    const float4 x4b = *(const float4*)(xrow + 4);

    if (t == 0) {
      hs[hsw] = h0[tid];
    } else {
      const unsigned want = (unsigned)t;
      const unsigned long long* src = hbuf64 + (size_t)(t & 1) * 1024 + tid;
      unsigned long long v;
      do {
        v = __hip_atomic_load(src, __ATOMIC_RELAXED, __HIP_MEMORY_SCOPE_AGENT);
      } while ((unsigned)(v >> 32) != want);
      hs[hsw] = __uint_as_float((unsigned)(v & 0xffffffffu));
    }
    __syncthreads();

    // partial matvec: (W_ih x_t + W_hh h_t) for this wave's m-slice of dim dw
    float a0, a1, a2, a3;
    {
      a0 = wx[0][0].x * x4a.x + wx[0][0].y * x4a.y +
           wx[0][0].z * x4a.z + wx[0][0].w * x4a.w +
           wx[0][1].x * x4b.x + wx[0][1].y * x4b.y +
           wx[0][1].z * x4b.z + wx[0][1].w * x4b.w;
      a1 = wx[1][0].x * x4a.x + wx[1][0].y * x4a.y +
           wx[1][0].z * x4a.z + wx[1][0].w * x4a.w +
           wx[1][1].x * x4b.x + wx[1][1].y * x4b.y +
           wx[1][1].z * x4b.z + wx[1][1].w * x4b.w;
      a2 = wx[2][0].x * x4a.x + wx[2][0].y * x4a.y +
           wx[2][0].z * x4a.z + wx[2][0].w * x4a.w +
           wx[2][1].x * x4b.x + wx[2][1].y * x4b.y +
           wx[2][1].z * x4b.z + wx[2][1].w * x4b.w;
      a3 = wx[3][0].x * x4a.x + wx[3][0].y * x4a.y +
           wx[3][0].z * x4a.z + wx[3][0].w * x4a.w +
           wx[3][1].x * x4b.x + wx[3][1].y * x4b.y +
           wx[3][1].z * x4b.z + wx[3][1].w * x4b.w;
      const float4 h4a = *(const float4*)&hs[idx0];
      const float4 h4b = *(const float4*)&hs[idx1];
      a0 += w4[0][0].x * h4a.x; a0 += w4[0][0].y * h4a.y;
      a0 += w4[0][0].z * h4a.z; a0 += w4[0][0].w * h4a.w;
      a0 += w4[0][1].x * h4b.x; a0 += w4[0][1].y * h4b.y;
      a0 += w4[0][1].z * h4b.z; a0 += w4[0][1].w * h4b.w;
      a1 += w4[1][0].x * h4a.x; a1 += w4[1][0].y * h4a.y;
      a1 += w4[1][0].z * h4a.z; a1 += w4[1][0].w * h4a.w;
      a1 += w4[1][1].x * h4b.x; a1 += w4[1][1].y * h4b.y;
      a1 += w4[1][1].z * h4b.z; a1 += w4[1][1].w * h4b.w;
      a2 += w4[2][0].x * h4a.x; a2 += w4[2][0].y * h4a.y;
      a2 += w4[2][0].z * h4a.z; a2 += w4[2][0].w * h4a.w;
      a2 += w4[2][1].x * h4b.x; a2 += w4[2][1].y * h4b.y;
      a2 += w4[2][1].z * h4b.z; a2 += w4[2][1].w * h4b.w;
      a3 += w4[3][0].x * h4a.x; a3 += w4[3][0].y * h4a.y;
      a3 += w4[3][0].z * h4a.z; a3 += w4[3][0].w * h4a.w;
      a3 += w4[3][1].x * h4b.x; a3 += w4[3][1].y * h4b.y;
      a3 += w4[3][1].z * h4b.z; a3 += w4[3][1].w * h4b.w;
    }
    a0 = wave_sum63(a0);
    a1 = wave_sum63(a1);
    a2 = wave_sum63(a2);
    a3 = wave_sum63(a3);
    if (ln == 63) gpart[wv] = float4{a0, a1, a2, a3};
    __syncthreads();   // gpart ready; also retires hs reads before next writes

    if (tid < 8) {
      const float4 g0 = gpart[tid];
      const float4 g1 = gpart[tid + 8];
      const float iv = g0.x + g1.x + bias[0];
      const float fv = g0.y + g1.y + bias[1];
      const float gg = g0.z + g1.z + bias[2];
      const float ov = g0.w + g1.w + bias[3];
      const float cn = sigmf(fv) * creg + sigmf(iv) * tanhf(gg);
      const float hn = sigmf(ov) * tanhf(cn);
      creg = cn; hreg = hn;
      const unsigned long long pv =
          ((unsigned long long)(unsigned)(t + 1) << 32) |
          (unsigned long long)__float_as_uint(hn);
      __hip_atomic_store(&hbuf64[(size_t)((t + 1) & 1) * 1024 + b * 8 + tid], pv,
                         __ATOMIC_RELAXED, __HIP_MEMORY_SCOPE_AGENT);
    }
  }

  // publish final h, c into dedicated tagged buffers (tag == 1; poison never matches)
  if (tid < 8) {
    const unsigned long long ph = (1ull << 32) | (unsigned long long)__float_as_uint(hreg);
    const unsigned long long pc = (1ull << 32) | (unsigned long long)__float_as_uint(creg);
    __hip_atomic_store(&hfin64[b * 8 + tid], ph, __ATOMIC_RELAXED, __HIP_MEMORY_SCOPE_AGENT);
    __hip_atomic_store(&cfin64[b * 8 + tid], pc, __ATOMIC_RELAXED, __HIP_MEMORY_SCOPE_AGENT);
  }

  // gather full hc = concat(h, c)
  {
    unsigned long long vh, vc;
    do {
      vh = __hip_atomic_load(&hfin64[tid], __ATOMIC_RELAXED, __HIP_MEMORY_SCOPE_AGENT);
    } while ((unsigned)(vh >> 32) != 1u);
    do {
      vc = __hip_atomic_load(&cfin64[tid], __ATOMIC_RELAXED, __HIP_MEMORY_SCOPE_AGENT);
    } while ((unsigned)(vc >> 32) != 1u);
    hcs[tid] = __uint_as_float((unsigned)(vh & 0xffffffffu));
    hcs[1024 + tid] = __uint_as_float((unsigned)(vc & 0xffffffffu));
  }
  __syncthreads();

  // projections: block b computes mean[b], logv[b] (2048-dot each)
  float hc1 = hcs[tid];
  float hc2 = hcs[1024 + tid];
  float pm = Wm[(size_t)b * 2048 + tid] * hc1 + Wm[(size_t)b * 2048 + 1024 + tid] * hc2;
  float pl = Wl[(size_t)b * 2048 + tid] * hc1 + Wl[(size_t)b * 2048 + 1024 + tid] * hc2;
#pragma unroll
  for (int o = 32; o > 0; o >>= 1) {
    pm += __shfl_down(pm, o);
    pl += __shfl_down(pl, o);
  }
  if (ln == 0) { rs[wv] = pm; rs[16 + wv] = pl; }
  __syncthreads();
  if (tid == 0) {
    float m = 0.0f, l = 0.0f;
    for (int i = 0; i < 16; i++) { m += rs[i]; l += rs[16 + i]; }
    m += bm[b];
    l += bl[b];
    float z = eps[b] * expf(0.5f * l) + m;
    out[b] = z;
    out[LAT + b] = m;
    out[2 * LAT + b] = l;
  }
}

extern "C" void kernel_launch(void* const* d_in, const int* in_sizes, int n_in,
                              void* d_out, int out_size, void* d_ws, size_t ws_size,
                              hipStream_t stream) {
  const int*   tok = (const int*)d_in[0];
  const float* h0  = (const float*)d_in[1];
  const float* c0  = (const float*)d_in[2];
  const float* eps = (const float*)d_in[3];
  const float* emb = (const float*)d_in[4];
  const float* Wih = (const float*)d_in[5];
  const float* Whh = (const float*)d_in[6];
  const float* bih = (const float*)d_in[7];
  const float* bhh = (const float*)d_in[8];
  const float* Wm  = (const float*)d_in[9];
  const float* bm  = (const float*)d_in[10];
  const float* Wl  = (const float*)d_in[11];
  const float* bl  = (const float*)d_in[12];
  float* out = (float*)d_out;

  char* ws = (char*)d_ws;
  unsigned long long* hbuf64 = (unsigned long long*)(ws + WS_HBUF);
  unsigned long long* hfin64 = (unsigned long long*)(ws + WS_HFIN);
  unsigned long long* cfin64 = (unsigned long long*)(ws + WS_CFIN);

  void* args[] = {(void*)&tok, (void*)&h0, (void*)&c0, (void*)&eps,
                  (void*)&emb, (void*)&Wih, (void*)&Whh, (void*)&bih, (void*)&bhh,
                  (void*)&Wm, (void*)&bm, (void*)&Wl, (void*)&bl,
                  (void*)&hbuf64, (void*)&hfin64, (void*)&cfin64, (void*)&out};
  hipLaunchCooperativeKernel((void*)lstm_k, dim3(NBLK), dim3(1024), args, 0, stream);
}

// Round 5
// 2343.930 us; speedup vs baseline: 1.1779x; 1.0079x over previous
//
#include <hip/hip_runtime.h>
#include <cstdint>
#include <cstddef>

#define T_LEN 1024
#define CH    1024
#define LAT   128
#define NBLK  128   // LSTM blocks; block b owns hidden dims [b*8, b*8+8)

// ---------------- ws layout (bytes) ----------------
// [+16 MiB]     : hbuf64[2][1024]    tagged h broadcast (u64: tag<<32 | bits)
// [+16 KiB]     : hfin64[1024]       tagged final h (tag==1)
// [+24 KiB]     : cfin64[1024]       tagged final c (tag==1)
#define WS_HBUF  (16777216)
#define WS_HFIN  (16777216 + 16384)
#define WS_CFIN  (16777216 + 24576)

// LDS swizzle: logical float j stored at j ^ (((j>>4)&7)<<2).
// Read side: thread ln reads k = ln*16 + 4m; (k>>4)&7 == ln&7, so the
// physical 16B-slot index is ((4ln+m)&7) ^ (ln&7) — distinct across every
// 8 consecutive lanes for fixed m (enumerated: m=0 -> {0,5,2,7,4,1,6,3}).
// Write side: b32 writes, bank = bijective xor of low 5 bits -> conflict-free.
// Bits 0-1 untouched -> float4 contiguity and 16B alignment preserved.
#define SWZ(j) ((j) ^ ((((j) >> 4) & 7) << 2))

// ---- fast gate math: v_exp_f32 (2^x) + v_rcp_f32 (round-3 validated) ----
#define LOG2E 1.44269504088896340736f
__device__ __forceinline__ float fsig(float x) {   // 1/(1+e^-x)
  return __builtin_amdgcn_rcpf(1.0f + __builtin_amdgcn_exp2f(-LOG2E * x));
}
__device__ __forceinline__ float ftanh(float x) {  // 1 - 2/(e^{2x}+1)
  float e = __builtin_amdgcn_exp2f(2.0f * LOG2E * x);
  return 1.0f - 2.0f * __builtin_amdgcn_rcpf(e + 1.0f);
}

__device__ __forceinline__ float dot4(float4 a, float4 b) {
  return a.x * b.x + a.y * b.y + a.z * b.z + a.w * b.w;
}

template <int CTRL, int RM>
__device__ __forceinline__ float dpp_add(float x) {
  int t = __builtin_amdgcn_update_dpp(0, __float_as_int(x), CTRL, RM, 0xf, true);
  return x + __int_as_float(t);
}

// 64-lane sum via DPP (VALU pipe only, no DS ops). Result valid in lane 63.
__device__ __forceinline__ float wave_sum63(float x) {
  x = dpp_add<0x111, 0xf>(x);   // row_shr:1
  x = dpp_add<0x112, 0xf>(x);   // row_shr:2
  x = dpp_add<0x114, 0xf>(x);   // row_shr:4
  x = dpp_add<0x118, 0xf>(x);   // row_shr:8  -> lane15 of each row = row sum
  x = dpp_add<0x142, 0xa>(x);   // row_bcast:15 -> rows 1,3
  x = dpp_add<0x143, 0xc>(x);   // row_bcast:31 -> rows 2,3; lane 63 = total
  return x;
}

__device__ __forceinline__ unsigned long long apoll(const unsigned long long* p) {
  return __hip_atomic_load(p, __ATOMIC_RELAXED, __HIP_MEMORY_SCOPE_AGENT);
}
__device__ __forceinline__ void apub(unsigned long long* p, unsigned tag, float v) {
  const unsigned long long pv =
      ((unsigned long long)tag << 32) | (unsigned long long)__float_as_uint(v);
  __hip_atomic_store(p, pv, __ATOMIC_RELAXED, __HIP_MEMORY_SCOPE_AGENT);
}

// ---------------- fused kernel: 128 blocks x 512 threads (8 waves) ----------------
// Wave d owns dim b*8+d COMPLETELY: lane ln covers k in [ln*16, ln*16+16) for
// all 4 gate rows. DPP reduce lands complete i,f,g,o in lane 63, which applies
// gates and publishes immediately — no gpart buffer, no second barrier, no
// tid<8 gather stage. x-dot + weight access issue before the poll (independent
// of h). One barrier/step; hs[2][1024] double-buffered (D=2: a wave writes
// hs[pb] at step t+2 only after passing barrier t+1, which readers of step t
// joined only after finishing their hs[pb] reads).
//
// Plain (non-cooperative) launch: 8 waves/block at >=2 waves/EU bound means
// every CU hosts >=2 blocks' worth of resources; 128 blocks on 256 CUs are
// all resident immediately, which is all the polling protocol requires.
//
// Cross-block h exchange: fence-free tagged 64-bit relaxed agent-scope atomics.
// Payload = (tag<<32)|float_bits; tag t+1 published into slot (t+1)&1.
// D=2 slot reuse is race-free: publishing tag t+2 requires having consumed
// ALL tags t+1, which implies every block finished reading slot t&1.
__global__ __launch_bounds__(512, 2) void lstm_k(const int* __restrict__ tok,
                                                 const float* __restrict__ h0,
                                                 const float* __restrict__ c0,
                                                 const float* __restrict__ eps,
                                                 const float* __restrict__ emb,
                                                 const float* __restrict__ Wih,
                                                 const float* __restrict__ Whh,
                                                 const float* __restrict__ bih,
                                                 const float* __restrict__ bhh,
                                                 const float* __restrict__ Wm,
                                                 const float* __restrict__ bm,
                                                 const float* __restrict__ Wl,
                                                 const float* __restrict__ bl,
                                                 unsigned long long* __restrict__ hbuf64,
                                                 unsigned long long* __restrict__ hfin64,
                                                 unsigned long long* __restrict__ cfin64,
                                                 float* __restrict__ out) {
  __shared__ float hs[2][1024];
  __shared__ float hcs[2048];
  __shared__ float rs[16];
  __shared__ int red[512];

  const int tid = threadIdx.x;
  const int b = blockIdx.x;
  const int wv = tid >> 6;            // wave 0..7 == dim within block
  const int ln = tid & 63;            // lane
  const int kbase = ln * 16;          // this thread's 16-float k-window
  const int swzm = (ln & 7) << 2;

  // ---- eos index (each block computes it redundantly) ----
  {
    int v0 = (tok[tid] == 1) ? tid : 0x7fffffff;
    int v1 = (tok[tid + 512] == 1) ? (tid + 512) : 0x7fffffff;
    red[tid] = min(v0, v1);
  }
  __syncthreads();
  for (int s = 256; s > 0; s >>= 1) {
    if (tid < s) red[tid] = min(red[tid], red[tid + s]);
    __syncthreads();
  }
  const int e0 = red[0];
  const int eos = (e0 == 0x7fffffff) ? 0 : e0;
  __syncthreads();

  // ---- weight fragments: rows q*1024 + b*8 + wv, k in [kbase, kbase+16) ----
  float4 wh[4][4];   // W_hh slice: 64 floats
  float4 wx[4][4];   // W_ih slice: 64 floats
#pragma unroll
  for (int q = 0; q < 4; q++) {
    const size_t roff = (size_t)(q * 1024 + b * 8 + wv) * CH + kbase;
#pragma unroll
    for (int m = 0; m < 4; m++) {
      wh[q][m] = *(const float4*)(Whh + roff + 4 * m);
      wx[q][m] = *(const float4*)(Wih + roff + 4 * m);
    }
  }

  // ---- lane-63 per-dim state: biases, h, c ----
  float bias0 = 0.f, bias1 = 0.f, bias2 = 0.f, bias3 = 0.f;
  float hreg = 0.f, creg = 0.f;
  if (ln == 63) {
    const int d = b * 8 + wv;
    bias0 = bih[d] + bhh[d];
    bias1 = bih[1024 + d] + bhh[1024 + d];
    bias2 = bih[2048 + d] + bhh[2048 + d];
    bias3 = bih[3072 + d] + bhh[3072 + d];
    hreg = h0[d];
    creg = c0[d];
  }

  for (int t = 0; t < eos; t++) {
    const int pb = t & 1;

    // ---- x-dot: independent of h, runs before/during the poll wait ----
    float a0, a1, a2, a3;
    {
      const float* xrow = emb + (size_t)tok[t] * CH + kbase;
      float4 xv0 = *(const float4*)(xrow);
      float4 xv1 = *(const float4*)(xrow + 4);
      float4 xv2 = *(const float4*)(xrow + 8);
      float4 xv3 = *(const float4*)(xrow + 12);
      a0 = dot4(wx[0][0], xv0) + dot4(wx[0][1], xv1) +
           dot4(wx[0][2], xv2) + dot4(wx[0][3], xv3);
      a1 = dot4(wx[1][0], xv0) + dot4(wx[1][1], xv1) +
           dot4(wx[1][2], xv2) + dot4(wx[1][3], xv3);
      a2 = dot4(wx[2][0], xv0) + dot4(wx[2][1], xv1) +
           dot4(wx[2][2], xv2) + dot4(wx[2][3], xv3);
      a3 = dot4(wx[3][0], xv0) + dot4(wx[3][1], xv1) +
           dot4(wx[3][2], xv2) + dot4(wx[3][3], xv3);
    }

    // ---- poll this thread's two h words into hs[pb] ----
    if (t == 0) {
      hs[0][SWZ(2 * tid)] = h0[2 * tid];
      hs[0][SWZ(2 * tid + 1)] = h0[2 * tid + 1];
    } else {
      const unsigned want = (unsigned)t;
      const unsigned long long* src = hbuf64 + (size_t)pb * 1024 + 2 * tid;
      unsigned long long v0, v1;
      do { v0 = apoll(src); } while ((unsigned)(v0 >> 32) != want);
      do { v1 = apoll(src + 1); } while ((unsigned)(v1 >> 32) != want);
      hs[pb][SWZ(2 * tid)] = __uint_as_float((unsigned)(v0 & 0xffffffffu));
      hs[pb][SWZ(2 * tid + 1)] = __uint_as_float((unsigned)(v1 & 0xffffffffu));
    }
    __syncthreads();   // the only barrier in the step

    // ---- h-dot: wave wv's dim, conflict-free swizzled b128 reads ----
#pragma unroll
    for (int m = 0; m < 4; m++) {
      const float4 h4 = *(const float4*)&hs[pb][(kbase + 4 * m) ^ swzm];
      a0 += dot4(wh[0][m], h4);
      a1 += dot4(wh[1][m], h4);
      a2 += dot4(wh[2][m], h4);
      a3 += dot4(wh[3][m], h4);
    }
    a0 = wave_sum63(a0);
    a1 = wave_sum63(a1);
    a2 = wave_sum63(a2);
    a3 = wave_sum63(a3);

    if (ln == 63) {
      const float iv = a0 + bias0, fv = a1 + bias1;
      const float gg = a2 + bias2, ov = a3 + bias3;
      const float cn = fsig(fv) * creg + fsig(iv) * ftanh(gg);
      const float hn = fsig(ov) * ftanh(cn);
      creg = cn; hreg = hn;
      apub(&hbuf64[(size_t)((t + 1) & 1) * 1024 + b * 8 + wv],
           (unsigned)(t + 1), hn);
    }
  }

  // publish final h, c (tag == 1; workspace poison never matches)
  if (ln == 63) {
    apub(&hfin64[b * 8 + wv], 1u, hreg);
    apub(&cfin64[b * 8 + wv], 1u, creg);
  }

  // gather full hc = concat(h, c): each thread polls 2 h words + 2 c words
  {
#pragma unroll
    for (int part = 0; part < 2; part++) {
      const int i = tid + part * 512;
      unsigned long long vh, vc;
      do { vh = apoll(&hfin64[i]); } while ((unsigned)(vh >> 32) != 1u);
      do { vc = apoll(&cfin64[i]); } while ((unsigned)(vc >> 32) != 1u);
      hcs[i] = __uint_as_float((unsigned)(vh & 0xffffffffu));
      hcs[1024 + i] = __uint_as_float((unsigned)(vc & 0xffffffffu));
    }
  }
  __syncthreads();

  // projections: block b computes mean[b], logv[b] (2048-dot each)
  float pm = 0.f, pl = 0.f;
#pragma unroll
  for (int part = 0; part < 4; part++) {
    const int j = tid + part * 512;
    const float hcv = hcs[j];
    pm += Wm[(size_t)b * 2048 + j] * hcv;
    pl += Wl[(size_t)b * 2048 + j] * hcv;
  }
#pragma unroll
  for (int o = 32; o > 0; o >>= 1) {
    pm += __shfl_down(pm, o);
    pl += __shfl_down(pl, o);
  }
  if (ln == 0) { rs[wv] = pm; rs[8 + wv] = pl; }
  __syncthreads();
  if (tid == 0) {
    float m = 0.0f, l = 0.0f;
    for (int i = 0; i < 8; i++) { m += rs[i]; l += rs[8 + i]; }
    m += bm[b];
    l += bl[b];
    const float z = eps[b] * expf(0.5f * l) + m;
    out[b] = z;
    out[LAT + b] = m;
    out[2 * LAT + b] = l;
  }
}

extern "C" void kernel_launch(void* const* d_in, const int* in_sizes, int n_in,
                              void* d_out, int out_size, void* d_ws, size_t ws_size,
                              hipStream_t stream) {
  const int*   tok = (const int*)d_in[0];
  const float* h0  = (const float*)d_in[1];
  const float* c0  = (const float*)d_in[2];
  const float* eps = (const float*)d_in[3];
  const float* emb = (const float*)d_in[4];
  const float* Wih = (const float*)d_in[5];
  const float* Whh = (const float*)d_in[6];
  const float* bih = (const float*)d_in[7];
  const float* bhh = (const float*)d_in[8];
  const float* Wm  = (const float*)d_in[9];
  const float* bm  = (const float*)d_in[10];
  const float* Wl  = (const float*)d_in[11];
  const float* bl  = (const float*)d_in[12];
  float* out = (float*)d_out;

  char* ws = (char*)d_ws;
  unsigned long long* hbuf64 = (unsigned long long*)(ws + WS_HBUF);
  unsigned long long* hfin64 = (unsigned long long*)(ws + WS_HFIN);
  unsigned long long* cfin64 = (unsigned long long*)(ws + WS_CFIN);

  lstm_k<<<dim3(NBLK), dim3(512), 0, stream>>>(
      tok, h0, c0, eps, emb, Wih, Whh, bih, bhh, Wm, bm, Wl, bl,
      hbuf64, hfin64, cfin64, out);
}